// Round 1
// baseline (83858.649 us; speedup 1.0000x reference)
//
#include <hip/hip_runtime.h>
#include <math.h>

#define BB 32
#define SS 256
#define EE 512
#define HH 1024
#define DD 2048
#define VV 10000

// ---------------------------------------------------------------------------
// ws layout (floats):
//   xeT : [S][E][B]   encoder inputs, transposed per step   (4,194,304)
//   hfT : [2][H][B]   fwd hidden ping-pong                  (65,536)
//   hbT : [2][H][B]   bwd hidden ping-pong                  (65,536)
//   cfT : [H][B]                                            (32,768)
//   cbT : [H][B]                                            (32,768)
//   hdT : [2][D][B]   decoder hidden ping-pong              (131,072)
//   cdT : [D][B]                                            (65,536)
//   outT: [D][B]      relu(bn(h))                           (65,536)
//   xdT : [E][B]      decoder input embedding, transposed   (16,384)
// total ~ 4.67M floats ~ 18.7 MB
// ---------------------------------------------------------------------------

#define FMA4(acc, q, x0, x1, x2, x3)                                          \
  acc = fmaf(q.x, x0, acc); acc = fmaf(q.y, x1, acc);                         \
  acc = fmaf(q.z, x2, acc); acc = fmaf(q.w, x3, acc);

__global__ __launch_bounds__(256) void k_zero(float* __restrict__ p, int n) {
  int i = blockIdx.x * 256 + threadIdx.x;
  if (i < n) p[i] = 0.0f;
}

// zero d_out[:, 0, :]
__global__ __launch_bounds__(256) void k_out0(float* __restrict__ out) {
  int i = blockIdx.x * 256 + threadIdx.x;
  if (i < BB * VV) {
    int b = i / VV, v = i % VV;
    out[(size_t)b * SS * VV + v] = 0.0f;
  }
}

// xeT[s][k][b] = emb[x[b][s]][k]
__global__ __launch_bounds__(256) void k_embed(const int* __restrict__ x,
                                               const float* __restrict__ emb,
                                               float* __restrict__ xeT) {
  int i = blockIdx.x * 256 + threadIdx.x;           // exact: S*E*B / 256 blocks
  int s = i / (EE * BB);
  int r = i % (EE * BB);
  int k = r / BB;
  int b = r & 31;
  xeT[i] = emb[(size_t)x[b * SS + s] * EE + k];
}

// xdT[k][b] = emb[x[b][0]][k]  (tok0)
__global__ __launch_bounds__(256) void k_gather0(const int* __restrict__ x,
                                                 const float* __restrict__ emb,
                                                 float* __restrict__ xdT) {
  int i = blockIdx.x * 256 + threadIdx.x;           // E*B / 256 blocks
  int k = i / BB, b = i & 31;
  xdT[i] = emb[(size_t)x[b * SS] * EE + k];
}

// One encoder time step, both directions. Block: 8 cells x 32 batch.
__global__ __launch_bounds__(256) void k_enc_step(
    int t, const float* __restrict__ xeT,
    float* __restrict__ hfT, float* __restrict__ cfT,
    float* __restrict__ hbT, float* __restrict__ cbT,
    const float* __restrict__ Wih_f, const float* __restrict__ Whh_f,
    const float* __restrict__ b_f,
    const float* __restrict__ Wih_b, const float* __restrict__ Whh_b,
    const float* __restrict__ b_b) {
  const int dir = blockIdx.y;
  const float* __restrict__ Wih  = dir ? Wih_b : Wih_f;
  const float* __restrict__ Whh  = dir ? Whh_b : Whh_f;
  const float* __restrict__ bias = dir ? b_b : b_f;
  float* hT = dir ? hbT : hfT;
  float* cT = dir ? cbT : cfT;
  const int s   = dir ? (SS - 1 - t) : t;
  const int pin = t & 1;
  const float* __restrict__ x   = xeT + (size_t)s * EE * BB;
  const float* __restrict__ hin = hT + pin * (HH * BB);
  float* __restrict__ hout      = hT + (pin ^ 1) * (HH * BB);

  const int j = blockIdx.x * 8 + (threadIdx.x >> 5);  // cell 0..H-1
  const int b = threadIdx.x & 31;

  float a0 = bias[j], a1 = bias[HH + j], a2 = bias[2 * HH + j], a3 = bias[3 * HH + j];

  {  // input projection, K = E
    const float4* __restrict__ w0 = (const float4*)(Wih + (size_t)j * EE);
    const float4* __restrict__ w1 = (const float4*)(Wih + (size_t)(HH + j) * EE);
    const float4* __restrict__ w2 = (const float4*)(Wih + (size_t)(2 * HH + j) * EE);
    const float4* __restrict__ w3 = (const float4*)(Wih + (size_t)(3 * HH + j) * EE);
#pragma unroll 4
    for (int k4 = 0; k4 < EE / 4; ++k4) {
      float4 q0 = w0[k4], q1 = w1[k4], q2 = w2[k4], q3 = w3[k4];
      const float* xp = x + k4 * 4 * BB + b;
      float x0 = xp[0], x1 = xp[BB], x2 = xp[2 * BB], x3 = xp[3 * BB];
      FMA4(a0, q0, x0, x1, x2, x3);
      FMA4(a1, q1, x0, x1, x2, x3);
      FMA4(a2, q2, x0, x1, x2, x3);
      FMA4(a3, q3, x0, x1, x2, x3);
    }
  }
  {  // recurrent projection, K = H
    const float4* __restrict__ w0 = (const float4*)(Whh + (size_t)j * HH);
    const float4* __restrict__ w1 = (const float4*)(Whh + (size_t)(HH + j) * HH);
    const float4* __restrict__ w2 = (const float4*)(Whh + (size_t)(2 * HH + j) * HH);
    const float4* __restrict__ w3 = (const float4*)(Whh + (size_t)(3 * HH + j) * HH);
#pragma unroll 4
    for (int k4 = 0; k4 < HH / 4; ++k4) {
      float4 q0 = w0[k4], q1 = w1[k4], q2 = w2[k4], q3 = w3[k4];
      const float* hp = hin + k4 * 4 * BB + b;
      float h0 = hp[0], h1 = hp[BB], h2 = hp[2 * BB], h3 = hp[3 * BB];
      FMA4(a0, q0, h0, h1, h2, h3);
      FMA4(a1, q1, h0, h1, h2, h3);
      FMA4(a2, q2, h0, h1, h2, h3);
      FMA4(a3, q3, h0, h1, h2, h3);
    }
  }
  float ig = 1.0f / (1.0f + expf(-a0));
  float fg = 1.0f / (1.0f + expf(-a1));
  float gg = tanhf(a2);
  float og = 1.0f / (1.0f + expf(-a3));
  const int idx = j * BB + b;
  float c = fmaf(fg, cT[idx], ig * gg);
  cT[idx] = c;
  hout[idx] = og * tanhf(c);
}

// hn = relu(bn(concat(hf, hb))) -> hdT parity 0
__global__ __launch_bounds__(256) void k_enc_bn(
    const float* __restrict__ hfT, const float* __restrict__ hbT,
    const float* __restrict__ gamma, const float* __restrict__ beta,
    float* __restrict__ hdT) {
  const int d = blockIdx.x * 8 + (threadIdx.x >> 5);
  const int b = threadIdx.x & 31;
  float v = (d < HH) ? hfT[d * BB + b] : hbT[(d - HH) * BB + b];
  float sum = v;
  for (int m = 16; m >= 1; m >>= 1) sum += __shfl_xor(sum, m, 32);
  float mean = sum * (1.0f / BB);
  float dx = v - mean;
  float s2 = dx * dx;
  for (int m = 16; m >= 1; m >>= 1) s2 += __shfl_xor(s2, m, 32);
  float var = s2 * (1.0f / BB);
  float y = dx * (1.0f / sqrtf(var + 1e-5f)) * gamma[d] + beta[d];
  hdT[d * BB + b] = fmaxf(y, 0.0f);
}

// Decoder gates + LSTM cell + fused BN + relu. Block: 8 cells x 32 batch.
__global__ __launch_bounds__(256) void k_dec_gates(
    int t, const float* __restrict__ xdT, float* __restrict__ hdT,
    float* __restrict__ cdT, float* __restrict__ outT,
    const float* __restrict__ Wih, const float* __restrict__ Whh,
    const float* __restrict__ bias,
    const float* __restrict__ gamma, const float* __restrict__ beta) {
  const int j = blockIdx.x * 8 + (threadIdx.x >> 5);  // cell 0..D-1
  const int b = threadIdx.x & 31;
  const int pin = t & 1;
  const float* __restrict__ hin = hdT + pin * (DD * BB);
  float* __restrict__ hout      = hdT + (pin ^ 1) * (DD * BB);

  float a0 = bias[j], a1 = bias[DD + j], a2 = bias[2 * DD + j], a3 = bias[3 * DD + j];

  {  // K = E over xdT
    const float4* __restrict__ w0 = (const float4*)(Wih + (size_t)j * EE);
    const float4* __restrict__ w1 = (const float4*)(Wih + (size_t)(DD + j) * EE);
    const float4* __restrict__ w2 = (const float4*)(Wih + (size_t)(2 * DD + j) * EE);
    const float4* __restrict__ w3 = (const float4*)(Wih + (size_t)(3 * DD + j) * EE);
#pragma unroll 4
    for (int k4 = 0; k4 < EE / 4; ++k4) {
      float4 q0 = w0[k4], q1 = w1[k4], q2 = w2[k4], q3 = w3[k4];
      const float* xp = xdT + k4 * 4 * BB + b;
      float x0 = xp[0], x1 = xp[BB], x2 = xp[2 * BB], x3 = xp[3 * BB];
      FMA4(a0, q0, x0, x1, x2, x3);
      FMA4(a1, q1, x0, x1, x2, x3);
      FMA4(a2, q2, x0, x1, x2, x3);
      FMA4(a3, q3, x0, x1, x2, x3);
    }
  }
  {  // K = D over hin
    const float4* __restrict__ w0 = (const float4*)(Whh + (size_t)j * DD);
    const float4* __restrict__ w1 = (const float4*)(Whh + (size_t)(DD + j) * DD);
    const float4* __restrict__ w2 = (const float4*)(Whh + (size_t)(2 * DD + j) * DD);
    const float4* __restrict__ w3 = (const float4*)(Whh + (size_t)(3 * DD + j) * DD);
#pragma unroll 4
    for (int k4 = 0; k4 < DD / 4; ++k4) {
      float4 q0 = w0[k4], q1 = w1[k4], q2 = w2[k4], q3 = w3[k4];
      const float* hp = hin + k4 * 4 * BB + b;
      float h0 = hp[0], h1 = hp[BB], h2 = hp[2 * BB], h3 = hp[3 * BB];
      FMA4(a0, q0, h0, h1, h2, h3);
      FMA4(a1, q1, h0, h1, h2, h3);
      FMA4(a2, q2, h0, h1, h2, h3);
      FMA4(a3, q3, h0, h1, h2, h3);
    }
  }
  float ig = 1.0f / (1.0f + expf(-a0));
  float fg = 1.0f / (1.0f + expf(-a1));
  float gg = tanhf(a2);
  float og = 1.0f / (1.0f + expf(-a3));
  const int idx = j * BB + b;
  float c = fmaf(fg, cdT[idx], ig * gg);
  cdT[idx] = c;
  float h = og * tanhf(c);
  hout[idx] = h;

  // fused BN over batch (32 lanes with same feature j) + relu
  float sum = h;
  for (int m = 16; m >= 1; m >>= 1) sum += __shfl_xor(sum, m, 32);
  float mean = sum * (1.0f / BB);
  float dx = h - mean;
  float s2 = dx * dx;
  for (int m = 16; m >= 1; m >>= 1) s2 += __shfl_xor(s2, m, 32);
  float var = s2 * (1.0f / BB);
  float y = dx * (1.0f / sqrtf(var + 1e-5f)) * gamma[j] + beta[j];
  outT[idx] = fmaxf(y, 0.0f);
}

// logits[b][v] = fcb[v] + outT[:,b] . fcW[v,:]; store to d_out[b][t+1][v]
__global__ __launch_bounds__(256) void k_fc(int t, const float* __restrict__ outT,
                                            const float* __restrict__ fcW,
                                            const float* __restrict__ fcb,
                                            float* __restrict__ out) {
  const int v = blockIdx.x * 8 + (threadIdx.x >> 5);  // 1250*8 = 10000 exact
  const int b = threadIdx.x & 31;
  float acc = fcb[v];
  const float4* __restrict__ w = (const float4*)(fcW + (size_t)v * DD);
#pragma unroll 4
  for (int k4 = 0; k4 < DD / 4; ++k4) {
    float4 q = w[k4];
    const float* xp = outT + k4 * 4 * BB + b;
    FMA4(acc, q, xp[0], xp[BB], xp[2 * BB], xp[3 * BB]);
  }
  out[(size_t)b * SS * VV + (size_t)(t + 1) * VV + v] = acc;
}

// per-batch-row argmax over logits (first-max tie rule), then gather embedding
__global__ __launch_bounds__(256) void k_argmax_gather(int t,
                                                       const float* __restrict__ out,
                                                       const float* __restrict__ emb,
                                                       float* __restrict__ xdT) {
  const int b = blockIdx.x;
  const float* __restrict__ row = out + (size_t)b * SS * VV + (size_t)(t + 1) * VV;
  float mv = -INFINITY;
  int mi = 0x7fffffff;
  for (int v = threadIdx.x; v < VV; v += 256) {
    float val = row[v];
    if (val > mv || (val == mv && v < mi)) { mv = val; mi = v; }
  }
  for (int m = 32; m >= 1; m >>= 1) {
    float ov = __shfl_xor(mv, m);
    int oi = __shfl_xor(mi, m);
    if (ov > mv || (ov == mv && oi < mi)) { mv = ov; mi = oi; }
  }
  __shared__ float sv[4];
  __shared__ int si[4];
  __shared__ int stok;
  int w = threadIdx.x >> 6;
  if ((threadIdx.x & 63) == 0) { sv[w] = mv; si[w] = mi; }
  __syncthreads();
  if (threadIdx.x == 0) {
    mv = sv[0]; mi = si[0];
    for (int i = 1; i < 4; ++i)
      if (sv[i] > mv || (sv[i] == mv && si[i] < mi)) { mv = sv[i]; mi = si[i]; }
    stok = mi;
  }
  __syncthreads();
  const int tok = stok;
  for (int k = threadIdx.x; k < EE; k += 256)
    xdT[k * BB + b] = emb[(size_t)tok * EE + k];
}

extern "C" void kernel_launch(void* const* d_in, const int* in_sizes, int n_in,
                              void* d_out, int out_size, void* d_ws, size_t ws_size,
                              hipStream_t stream) {
  const int*   x         = (const int*)d_in[0];
  const float* emb       = (const float*)d_in[1];
  const float* Wih_f     = (const float*)d_in[2];
  const float* Whh_f     = (const float*)d_in[3];
  const float* b_f       = (const float*)d_in[4];
  const float* Wih_b     = (const float*)d_in[5];
  const float* Whh_b     = (const float*)d_in[6];
  const float* b_b       = (const float*)d_in[7];
  const float* Wih_d     = (const float*)d_in[8];
  const float* Whh_d     = (const float*)d_in[9];
  const float* b_d       = (const float*)d_in[10];
  const float* enc_gamma = (const float*)d_in[11];
  const float* enc_beta  = (const float*)d_in[12];
  const float* dec_gamma = (const float*)d_in[13];
  const float* dec_beta  = (const float*)d_in[14];
  const float* fcW       = (const float*)d_in[15];
  const float* fcb       = (const float*)d_in[16];
  float* out = (float*)d_out;
  float* ws  = (float*)d_ws;

  size_t off = 0;
  float* xeT = ws + off; off += (size_t)SS * EE * BB;
  float* hfT = ws + off; off += 2 * HH * BB;
  float* hbT = ws + off; off += 2 * HH * BB;
  float* cfT = ws + off; off += HH * BB;
  float* cbT = ws + off; off += HH * BB;
  float* hdT = ws + off; off += 2 * DD * BB;
  float* cdT = ws + off; off += DD * BB;
  float* outT = ws + off; off += DD * BB;
  float* xdT = ws + off; off += EE * BB;

  // zero hfT..cdT (contiguous; 393216 floats) — h ping-pong p0 + c states
  const int nz = 2 * HH * BB * 2 + HH * BB * 2 + 2 * DD * BB + DD * BB;
  k_zero<<<(nz + 255) / 256, 256, 0, stream>>>(hfT, nz);
  k_out0<<<(BB * VV + 255) / 256, 256, 0, stream>>>(out);
  k_embed<<<(SS * EE * BB) / 256, 256, 0, stream>>>(x, emb, xeT);
  k_gather0<<<(EE * BB) / 256, 256, 0, stream>>>(x, emb, xdT);

  for (int t = 0; t < SS; ++t)
    k_enc_step<<<dim3(HH / 8, 2), 256, 0, stream>>>(t, xeT, hfT, cfT, hbT, cbT,
                                                    Wih_f, Whh_f, b_f,
                                                    Wih_b, Whh_b, b_b);

  k_enc_bn<<<DD / 8, 256, 0, stream>>>(hfT, hbT, enc_gamma, enc_beta, hdT);

  for (int t = 0; t < SS - 1; ++t) {
    k_dec_gates<<<DD / 8, 256, 0, stream>>>(t, xdT, hdT, cdT, outT,
                                            Wih_d, Whh_d, b_d, dec_gamma, dec_beta);
    k_fc<<<VV / 8, 256, 0, stream>>>(t, outT, fcW, fcb, out);
    k_argmax_gather<<<BB, 256, 0, stream>>>(t, out, emb, xdT);
  }
}

// Round 3
// 76421.899 us; speedup vs baseline: 1.0973x; 1.0973x over previous
//
#include <hip/hip_runtime.h>
#include <math.h>

#define BB 32
#define SS 256
#define EE 512
#define HH 1024
#define DD 2048
#define VV 10000
#define KS 4

// ---------------------------------------------------------------------------
// ws layout (floats). All activation tensors interleaved [K/4][B][4] so a
// thread's activation load is one coalesced float4 (lane b -> 16B, 512B/group).
//   xeT : [S][E/4][B][4]  encoder inputs                    (4,194,304)
//   hfT : [2][H/4][B][4]  fwd hidden ping-pong              (65,536)
//   hbT : [2][H/4][B][4]                                    (65,536)
//   cfT : [H][B]                                            (32,768)
//   cbT : [H][B]                                            (32,768)
//   hdT : [2][D/4][B][4]  decoder hidden ping-pong          (131,072)
//   cdT : [D][B]                                            (65,536)
//   outT: [D/4][B][4]     relu(bn(h))                       (65,536)
//   xdT : [E/4][B][4]     decoder input embedding           (16,384)
// ---------------------------------------------------------------------------

// NOTE: macro params must not collide with .x/.y/.z/.w member tokens!
#define DOT4(acc, q, r)                                                       \
  acc = fmaf((q).x, (r).x, acc); acc = fmaf((q).y, (r).y, acc);               \
  acc = fmaf((q).z, (r).z, acc); acc = fmaf((q).w, (r).w, acc);

__global__ __launch_bounds__(256) void k_zero(float* __restrict__ p, int n) {
  int i = blockIdx.x * 256 + threadIdx.x;
  if (i < n) p[i] = 0.0f;
}

// zero d_out[:, 0, :]
__global__ __launch_bounds__(256) void k_out0(float* __restrict__ out) {
  int i = blockIdx.x * 256 + threadIdx.x;
  if (i < BB * VV) {
    int b = i / VV, v = i % VV;
    out[(size_t)b * SS * VV + v] = 0.0f;
  }
}

// xeT[s][k4][b][c] = emb[x[b][s]][4*k4+c]
__global__ __launch_bounds__(256) void k_embed(const int* __restrict__ x,
                                               const float* __restrict__ emb,
                                               float* __restrict__ xeT) {
  int i = blockIdx.x * 256 + threadIdx.x;           // exact: S*E*B / 256 blocks
  int s = i / (EE * BB);
  int r = i % (EE * BB);
  int k = (r >> 7) * 4 + (r & 3);
  int b = (r >> 2) & 31;
  xeT[i] = emb[(size_t)x[b * SS + s] * EE + k];
}

// xdT[k4][b][c] = emb[x[b][0]][4*k4+c]
__global__ __launch_bounds__(256) void k_gather0(const int* __restrict__ x,
                                                 const float* __restrict__ emb,
                                                 float* __restrict__ xdT) {
  int i = blockIdx.x * 256 + threadIdx.x;           // E*B / 256 blocks
  int k = (i >> 7) * 4 + (i & 3);
  int b = (i >> 2) & 31;
  xdT[i] = emb[(size_t)x[b * SS] * EE + k];
}

// One encoder time step, both directions. Block: 8 cells x 32 batch x KS ksplit.
__global__ __launch_bounds__(1024) void k_enc_step(
    int t, const float* __restrict__ xeT,
    float* __restrict__ hfT, float* __restrict__ cfT,
    float* __restrict__ hbT, float* __restrict__ cbT,
    const float* __restrict__ Wih_f, const float* __restrict__ Whh_f,
    const float* __restrict__ b_f,
    const float* __restrict__ Wih_b, const float* __restrict__ Whh_b,
    const float* __restrict__ b_b) {
  const int dir = blockIdx.y;
  const float* __restrict__ Wih  = dir ? Wih_b : Wih_f;
  const float* __restrict__ Whh  = dir ? Whh_b : Whh_f;
  const float* __restrict__ bias = dir ? b_b : b_f;
  float* hT = dir ? hbT : hfT;
  float* cT = dir ? cbT : cfT;
  const int s   = dir ? (SS - 1 - t) : t;
  const int pin = t & 1;
  const float* __restrict__ x   = xeT + (size_t)s * EE * BB;
  const float* __restrict__ hin = hT + pin * (HH * BB);
  float* __restrict__ hout      = hT + (pin ^ 1) * (HH * BB);

  const int tid = threadIdx.x;
  const int b = tid & 31, jj = (tid >> 5) & 7, ks = tid >> 8;
  const int j = blockIdx.x * 8 + jj;                 // cell 0..H-1

  float a0, a1, a2, a3;
  if (ks == 0) {
    a0 = bias[j]; a1 = bias[HH + j]; a2 = bias[2 * HH + j]; a3 = bias[3 * HH + j];
  } else {
    a0 = a1 = a2 = a3 = 0.0f;
  }

  {  // input projection chunk: k4 in [ks*32, ks*32+32)
    const float4* __restrict__ w0 = (const float4*)(Wih + (size_t)j * EE);
    const float4* __restrict__ w1 = (const float4*)(Wih + (size_t)(HH + j) * EE);
    const float4* __restrict__ w2 = (const float4*)(Wih + (size_t)(2 * HH + j) * EE);
    const float4* __restrict__ w3 = (const float4*)(Wih + (size_t)(3 * HH + j) * EE);
    const float4* __restrict__ xa = (const float4*)x;
    const int k4b = ks * (EE / 4 / KS), k4e = k4b + EE / 4 / KS;
#pragma unroll 4
    for (int k4 = k4b; k4 < k4e; ++k4) {
      float4 av = xa[k4 * BB + b];
      DOT4(a0, w0[k4], av); DOT4(a1, w1[k4], av);
      DOT4(a2, w2[k4], av); DOT4(a3, w3[k4], av);
    }
  }
  {  // recurrent projection chunk: k4 in [ks*64, ks*64+64)
    const float4* __restrict__ w0 = (const float4*)(Whh + (size_t)j * HH);
    const float4* __restrict__ w1 = (const float4*)(Whh + (size_t)(HH + j) * HH);
    const float4* __restrict__ w2 = (const float4*)(Whh + (size_t)(2 * HH + j) * HH);
    const float4* __restrict__ w3 = (const float4*)(Whh + (size_t)(3 * HH + j) * HH);
    const float4* __restrict__ ha = (const float4*)hin;
    const int k4b = ks * (HH / 4 / KS), k4e = k4b + HH / 4 / KS;
#pragma unroll 4
    for (int k4 = k4b; k4 < k4e; ++k4) {
      float4 av = ha[k4 * BB + b];
      DOT4(a0, w0[k4], av); DOT4(a1, w1[k4], av);
      DOT4(a2, w2[k4], av); DOT4(a3, w3[k4], av);
    }
  }

  __shared__ float4 red[KS - 1][8][32];
  if (ks) red[ks - 1][jj][b] = make_float4(a0, a1, a2, a3);
  __syncthreads();
  if (ks == 0) {
#pragma unroll
    for (int s2 = 0; s2 < KS - 1; ++s2) {
      float4 r4 = red[s2][jj][b];
      a0 += r4.x; a1 += r4.y; a2 += r4.z; a3 += r4.w;
    }
    float ig = 1.0f / (1.0f + expf(-a0));
    float fg = 1.0f / (1.0f + expf(-a1));
    float gg = tanhf(a2);
    float og = 1.0f / (1.0f + expf(-a3));
    const int idx = j * BB + b;
    float c = fmaf(fg, cT[idx], ig * gg);
    cT[idx] = c;
    hout[(j >> 2) * 128 + b * 4 + (j & 3)] = og * tanhf(c);
  }
}

// hn = relu(bn(concat(hf, hb))) -> hdT parity 0 (interleaved layout)
__global__ __launch_bounds__(256) void k_enc_bn(
    const float* __restrict__ hfT, const float* __restrict__ hbT,
    const float* __restrict__ gamma, const float* __restrict__ beta,
    float* __restrict__ hdT) {
  const int d = blockIdx.x * 8 + (threadIdx.x >> 5);
  const int b = threadIdx.x & 31;
  const int dl = (d < HH) ? d : d - HH;
  const float* __restrict__ src = (d < HH) ? hfT : hbT;
  float v = src[(dl >> 2) * 128 + b * 4 + (dl & 3)];
  float sum = v;
  for (int m = 16; m >= 1; m >>= 1) sum += __shfl_xor(sum, m, 32);
  float mean = sum * (1.0f / BB);
  float dx = v - mean;
  float s2 = dx * dx;
  for (int m = 16; m >= 1; m >>= 1) s2 += __shfl_xor(s2, m, 32);
  float var = s2 * (1.0f / BB);
  float y = dx * (1.0f / sqrtf(var + 1e-5f)) * gamma[d] + beta[d];
  hdT[(d >> 2) * 128 + b * 4 + (d & 3)] = fmaxf(y, 0.0f);
}

// Decoder gates + LSTM cell + fused BN + relu. Block: 8 cells x 32 b x KS.
__global__ __launch_bounds__(1024) void k_dec_gates(
    int t, const float* __restrict__ xdT, float* __restrict__ hdT,
    float* __restrict__ cdT, float* __restrict__ outT,
    const float* __restrict__ Wih, const float* __restrict__ Whh,
    const float* __restrict__ bias,
    const float* __restrict__ gamma, const float* __restrict__ beta) {
  const int tid = threadIdx.x;
  const int b = tid & 31, jj = (tid >> 5) & 7, ks = tid >> 8;
  const int j = blockIdx.x * 8 + jj;                 // cell 0..D-1
  const int pin = t & 1;
  const float* __restrict__ hin = hdT + pin * (DD * BB);
  float* __restrict__ hout      = hdT + (pin ^ 1) * (DD * BB);

  float a0, a1, a2, a3;
  if (ks == 0) {
    a0 = bias[j]; a1 = bias[DD + j]; a2 = bias[2 * DD + j]; a3 = bias[3 * DD + j];
  } else {
    a0 = a1 = a2 = a3 = 0.0f;
  }

  {  // K = E chunk over xdT: k4 in [ks*32, ks*32+32)
    const float4* __restrict__ w0 = (const float4*)(Wih + (size_t)j * EE);
    const float4* __restrict__ w1 = (const float4*)(Wih + (size_t)(DD + j) * EE);
    const float4* __restrict__ w2 = (const float4*)(Wih + (size_t)(2 * DD + j) * EE);
    const float4* __restrict__ w3 = (const float4*)(Wih + (size_t)(3 * DD + j) * EE);
    const float4* __restrict__ xa = (const float4*)xdT;
    const int k4b = ks * (EE / 4 / KS), k4e = k4b + EE / 4 / KS;
#pragma unroll 4
    for (int k4 = k4b; k4 < k4e; ++k4) {
      float4 av = xa[k4 * BB + b];
      DOT4(a0, w0[k4], av); DOT4(a1, w1[k4], av);
      DOT4(a2, w2[k4], av); DOT4(a3, w3[k4], av);
    }
  }
  {  // K = D chunk over hin: k4 in [ks*128, ks*128+128)
    const float4* __restrict__ w0 = (const float4*)(Whh + (size_t)j * DD);
    const float4* __restrict__ w1 = (const float4*)(Whh + (size_t)(DD + j) * DD);
    const float4* __restrict__ w2 = (const float4*)(Whh + (size_t)(2 * DD + j) * DD);
    const float4* __restrict__ w3 = (const float4*)(Whh + (size_t)(3 * DD + j) * DD);
    const float4* __restrict__ ha = (const float4*)hin;
    const int k4b = ks * (DD / 4 / KS), k4e = k4b + DD / 4 / KS;
#pragma unroll 4
    for (int k4 = k4b; k4 < k4e; ++k4) {
      float4 av = ha[k4 * BB + b];
      DOT4(a0, w0[k4], av); DOT4(a1, w1[k4], av);
      DOT4(a2, w2[k4], av); DOT4(a3, w3[k4], av);
    }
  }

  __shared__ float4 red[KS - 1][8][32];
  if (ks) red[ks - 1][jj][b] = make_float4(a0, a1, a2, a3);
  __syncthreads();
  if (ks == 0) {
#pragma unroll
    for (int s2 = 0; s2 < KS - 1; ++s2) {
      float4 r4 = red[s2][jj][b];
      a0 += r4.x; a1 += r4.y; a2 += r4.z; a3 += r4.w;
    }
    float ig = 1.0f / (1.0f + expf(-a0));
    float fg = 1.0f / (1.0f + expf(-a1));
    float gg = tanhf(a2);
    float og = 1.0f / (1.0f + expf(-a3));
    const int idx = j * BB + b;
    float c = fmaf(fg, cdT[idx], ig * gg);
    cdT[idx] = c;
    float h = og * tanhf(c);
    hout[(j >> 2) * 128 + b * 4 + (j & 3)] = h;

    // fused BN over batch (32 lanes share feature j) + relu
    float sum = h;
    for (int m = 16; m >= 1; m >>= 1) sum += __shfl_xor(sum, m, 32);
    float mean = sum * (1.0f / BB);
    float dx = h - mean;
    float s2v = dx * dx;
    for (int m = 16; m >= 1; m >>= 1) s2v += __shfl_xor(s2v, m, 32);
    float var = s2v * (1.0f / BB);
    float y = dx * (1.0f / sqrtf(var + 1e-5f)) * gamma[j] + beta[j];
    outT[(j >> 2) * 128 + b * 4 + (j & 3)] = fmaxf(y, 0.0f);
  }
}

// logits: 2 rows per thread sharing activation loads; store d_out[b][t+1][v]
__global__ __launch_bounds__(256) void k_fc(int t, const float* __restrict__ outT,
                                            const float* __restrict__ fcW,
                                            const float* __restrict__ fcb,
                                            float* __restrict__ out) {
  const int g = blockIdx.x * 8 + (threadIdx.x >> 5);  // 625*8 = 5000 groups
  const int v0 = g * 2;
  const int b = threadIdx.x & 31;
  float acc0 = fcb[v0], acc1 = fcb[v0 + 1];
  const float4* __restrict__ w0 = (const float4*)(fcW + (size_t)v0 * DD);
  const float4* __restrict__ w1 = (const float4*)(fcW + (size_t)(v0 + 1) * DD);
  const float4* __restrict__ xa = (const float4*)outT;
#pragma unroll 4
  for (int k4 = 0; k4 < DD / 4; ++k4) {
    float4 av = xa[k4 * BB + b];
    DOT4(acc0, w0[k4], av);
    DOT4(acc1, w1[k4], av);
  }
  const size_t base = (size_t)b * SS * VV + (size_t)(t + 1) * VV;
  out[base + v0] = acc0;
  out[base + v0 + 1] = acc1;
}

// per-batch-row argmax over logits (first-max tie rule), then gather embedding
__global__ __launch_bounds__(256) void k_argmax_gather(int t,
                                                       const float* __restrict__ out,
                                                       const float* __restrict__ emb,
                                                       float* __restrict__ xdT) {
  const int b = blockIdx.x;
  const float* __restrict__ row = out + (size_t)b * SS * VV + (size_t)(t + 1) * VV;
  const float4* __restrict__ row4 = (const float4*)row;
  float mv = -INFINITY;
  int mi = 0x7fffffff;
  for (int q = threadIdx.x; q < VV / 4; q += 256) {
    float4 v = row4[q];
    const int base = q * 4;
    if (v.x > mv) { mv = v.x; mi = base; }
    if (v.y > mv) { mv = v.y; mi = base + 1; }
    if (v.z > mv) { mv = v.z; mi = base + 2; }
    if (v.w > mv) { mv = v.w; mi = base + 3; }
  }
  for (int m = 32; m >= 1; m >>= 1) {
    float ov = __shfl_xor(mv, m);
    int oi = __shfl_xor(mi, m);
    if (ov > mv || (ov == mv && oi < mi)) { mv = ov; mi = oi; }
  }
  __shared__ float sv[4];
  __shared__ int si[4];
  __shared__ int stok;
  int w = threadIdx.x >> 6;
  if ((threadIdx.x & 63) == 0) { sv[w] = mv; si[w] = mi; }
  __syncthreads();
  if (threadIdx.x == 0) {
    mv = sv[0]; mi = si[0];
    for (int i = 1; i < 4; ++i)
      if (sv[i] > mv || (sv[i] == mv && si[i] < mi)) { mv = sv[i]; mi = si[i]; }
    stok = mi;
  }
  __syncthreads();
  const int tok = stok;
  for (int k = threadIdx.x; k < EE; k += 256)
    xdT[(k >> 2) * 128 + b * 4 + (k & 3)] = emb[(size_t)tok * EE + k];
}

extern "C" void kernel_launch(void* const* d_in, const int* in_sizes, int n_in,
                              void* d_out, int out_size, void* d_ws, size_t ws_size,
                              hipStream_t stream) {
  const int*   x         = (const int*)d_in[0];
  const float* emb       = (const float*)d_in[1];
  const float* Wih_f     = (const float*)d_in[2];
  const float* Whh_f     = (const float*)d_in[3];
  const float* b_f       = (const float*)d_in[4];
  const float* Wih_b     = (const float*)d_in[5];
  const float* Whh_b     = (const float*)d_in[6];
  const float* b_b       = (const float*)d_in[7];
  const float* Wih_d     = (const float*)d_in[8];
  const float* Whh_d     = (const float*)d_in[9];
  const float* b_d       = (const float*)d_in[10];
  const float* enc_gamma = (const float*)d_in[11];
  const float* enc_beta  = (const float*)d_in[12];
  const float* dec_gamma = (const float*)d_in[13];
  const float* dec_beta  = (const float*)d_in[14];
  const float* fcW       = (const float*)d_in[15];
  const float* fcb       = (const float*)d_in[16];
  float* out = (float*)d_out;
  float* ws  = (float*)d_ws;

  size_t off = 0;
  float* xeT = ws + off; off += (size_t)SS * EE * BB;
  float* hfT = ws + off; off += 2 * HH * BB;
  float* hbT = ws + off; off += 2 * HH * BB;
  float* cfT = ws + off; off += HH * BB;
  float* cbT = ws + off; off += HH * BB;
  float* hdT = ws + off; off += 2 * DD * BB;
  float* cdT = ws + off; off += DD * BB;
  float* outT = ws + off; off += DD * BB;
  float* xdT = ws + off; off += EE * BB;

  // zero hfT..cdT (contiguous) — h ping-pong + c states
  const int nz = 2 * HH * BB * 2 + HH * BB * 2 + 2 * DD * BB + DD * BB;
  k_zero<<<(nz + 255) / 256, 256, 0, stream>>>(hfT, nz);
  k_out0<<<(BB * VV + 255) / 256, 256, 0, stream>>>(out);
  k_embed<<<(SS * EE * BB) / 256, 256, 0, stream>>>(x, emb, xeT);
  k_gather0<<<(EE * BB) / 256, 256, 0, stream>>>(x, emb, xdT);

  for (int t = 0; t < SS; ++t)
    k_enc_step<<<dim3(HH / 8, 2), 1024, 0, stream>>>(t, xeT, hfT, cfT, hbT, cbT,
                                                     Wih_f, Whh_f, b_f,
                                                     Wih_b, Whh_b, b_b);

  k_enc_bn<<<DD / 8, 256, 0, stream>>>(hfT, hbT, enc_gamma, enc_beta, hdT);

  for (int t = 0; t < SS - 1; ++t) {
    k_dec_gates<<<DD / 8, 1024, 0, stream>>>(t, xdT, hdT, cdT, outT,
                                             Wih_d, Whh_d, b_d, dec_gamma, dec_beta);
    k_fc<<<625, 256, 0, stream>>>(t, outT, fcW, fcb, out);
    k_argmax_gather<<<BB, 256, 0, stream>>>(t, out, emb, xdT);
  }
}